// Round 2
// baseline (4185.500 us; speedup 1.0000x reference)
//
#include <hip/hip_runtime.h>
#include <hip/hip_bf16.h>
#include <math.h>

// ---- model dims ----
#define HIDN 768
#define NHEAD 12
#define DHEAD 64
#define WWIN 256
#define NCHUNK 16
#define NLAYER 2
#define FFND 3072
#define NLABEL 8921
#define NB 2
#define NS 4096
#define NBS (NB*NS)

typedef __attribute__((ext_vector_type(8))) short bf16x8;
typedef __attribute__((ext_vector_type(4))) float f32x4;

__device__ __forceinline__ float bf2f(unsigned short u){
  union { unsigned int i; float f; } v; v.i = ((unsigned int)u) << 16; return v.f;
}
__device__ __forceinline__ unsigned short f2bf(float f){
  __hip_bfloat16 h = __float2bfloat16(f);
  return *reinterpret_cast<unsigned short*>(&h);
}
__device__ __forceinline__ void unpack2(unsigned int u, float& a, float& b){
  union { unsigned int i; float f; } x, y;
  x.i = u << 16; y.i = u & 0xffff0000u; a = x.f; b = y.f;
}

// ---------------- embedding (fp32 inputs) ----------------
__global__ __launch_bounds__(256) void embed_k(const int* __restrict__ ids,
    const float* __restrict__ we, const float* __restrict__ pe,
    float* __restrict__ y){
  int i = blockIdx.x*256 + threadIdx.x;     // over NBS*HIDN exactly
  int row = i / HIDN; int d = i - row*HIDN;
  int s = row & (NS-1);
  int id = ids[row];
  y[i] = we[(size_t)id*HIDN + d] + pe[(size_t)s*HIDN + d];
}

// ---------------- layernorm (optional residual), fp32 + bf16 outputs ----------------
__global__ __launch_bounds__(256) void ln_k(const float* A, const float* R,
    const float* __restrict__ sc, const float* __restrict__ bi,
    float* X, unsigned short* XB){
  __shared__ float red[256];
  int row = blockIdx.x, t = threadIdx.x;
  size_t base = (size_t)row*HIDN;
  float v0 = A[base+t], v1 = A[base+t+256], v2 = A[base+t+512];
  if (R){ v0 += R[base+t]; v1 += R[base+t+256]; v2 += R[base+t+512]; }
  red[t] = v0+v1+v2; __syncthreads();
  for (int st=128; st>0; st>>=1){ if (t<st) red[t]+=red[t+st]; __syncthreads(); }
  float mean = red[0] * (1.0f/HIDN); __syncthreads();
  float d0=v0-mean, d1=v1-mean, d2=v2-mean;
  red[t] = d0*d0+d1*d1+d2*d2; __syncthreads();
  for (int st=128; st>0; st>>=1){ if (t<st) red[t]+=red[t+st]; __syncthreads(); }
  float rs = rsqrtf(red[0] * (1.0f/HIDN) + 1e-5f);
  float o0 = d0*rs*sc[t]     + bi[t];
  float o1 = d1*rs*sc[t+256] + bi[t+256];
  float o2 = d2*rs*sc[t+512] + bi[t+512];
  X[base+t]=o0; X[base+t+256]=o1; X[base+t+512]=o2;
  XB[base+t]=f2bf(o0); XB[base+t+256]=f2bf(o1); XB[base+t+512]=f2bf(o2);
}

// ---------------- fp32 [R,C] -> bf16 transpose [C,R] ----------------
__global__ __launch_bounds__(256) void transpose_k(const float* __restrict__ src,
    unsigned short* __restrict__ dst, int R, int C){
  __shared__ unsigned short tile[32][33];
  int ct = blockIdx.x*32, rt = blockIdx.y*32;
  int tx = threadIdx.x, ty = threadIdx.y;     // 32 x 8
  #pragma unroll
  for (int i=0;i<4;i++) tile[ty+i*8][tx] = f2bf(src[(size_t)(rt+ty+i*8)*C + ct + tx]);
  __syncthreads();
  #pragma unroll
  for (int i=0;i<4;i++) dst[(size_t)(ct+ty+i*8)*R + rt + tx] = tile[tx][ty+i*8];
}

// ---------------- GEMM: C[M,N] = A[M,K](bf16) * BT[N,K]^T (bf16) + bias(fp32) ----------------
template<int OUTF32, int GELU>
__global__ __launch_bounds__(256) void gemm_bt(const unsigned short* __restrict__ A,
    const unsigned short* __restrict__ BT, const float* __restrict__ bias,
    void* __restrict__ Cp, int M, int N, int K){
  __shared__ unsigned short As[64*32];
  __shared__ unsigned short Bs[64*32];
  int tid = threadIdx.x;
  int m0 = blockIdx.y*64, n0 = blockIdx.x*64;
  int r = tid >> 2, kc = (tid & 3) * 8;
  int lane = tid & 63, wid = tid >> 6;
  int waveM = (wid>>1)*32, waveN = (wid&1)*32;
  int m16 = lane & 15, quad = lane >> 4;
  f32x4 acc[2][2] = {};
  for (int kb=0; kb<K; kb+=32){
    uint4 av = *(const uint4*)(A  + (size_t)(m0+r)*K + kb + kc);
    uint4 bv = *(const uint4*)(BT + (size_t)(n0+r)*K + kb + kc);
    *(uint4*)(As + r*32 + kc) = av;
    *(uint4*)(Bs + r*32 + kc) = bv;
    __syncthreads();
    bf16x8 a0 = *(const bf16x8*)(As + (waveM + m16)*32 + quad*8);
    bf16x8 a1 = *(const bf16x8*)(As + (waveM + 16 + m16)*32 + quad*8);
    bf16x8 b0 = *(const bf16x8*)(Bs + (waveN + m16)*32 + quad*8);
    bf16x8 b1 = *(const bf16x8*)(Bs + (waveN + 16 + m16)*32 + quad*8);
    acc[0][0] = __builtin_amdgcn_mfma_f32_16x16x32_bf16(a0, b0, acc[0][0], 0,0,0);
    acc[0][1] = __builtin_amdgcn_mfma_f32_16x16x32_bf16(a0, b1, acc[0][1], 0,0,0);
    acc[1][0] = __builtin_amdgcn_mfma_f32_16x16x32_bf16(a1, b0, acc[1][0], 0,0,0);
    acc[1][1] = __builtin_amdgcn_mfma_f32_16x16x32_bf16(a1, b1, acc[1][1], 0,0,0);
    __syncthreads();
  }
  #pragma unroll
  for (int mi=0; mi<2; mi++)
  #pragma unroll
  for (int ni=0; ni<2; ni++){
    #pragma unroll
    for (int rg=0; rg<4; rg++){
      int row = m0 + waveM + mi*16 + quad*4 + rg;
      int col = n0 + waveN + ni*16 + m16;
      float v = acc[mi][ni][rg] + bias[col];
      if (GELU) v = 0.5f*v*(1.0f + erff(v*0.70710678118f));
      if (OUTF32) ((float*)Cp)[(size_t)row*N + col] = v;
      else ((unsigned short*)Cp)[(size_t)row*N + col] = f2bf(v);
    }
  }
}

// ---------------- banded sliding-window attention (+ global key column) ----------------
__global__ __launch_bounds__(256) void band_attn(
    const unsigned short* __restrict__ Q, const unsigned short* __restrict__ Kp,
    const unsigned short* __restrict__ Vp, const unsigned short* __restrict__ KG,
    const unsigned short* __restrict__ VG, const int* __restrict__ am,
    unsigned short* __restrict__ Out){
  __shared__ unsigned short Kt[128*64];
  __shared__ unsigned short Vt[128*64];
  __shared__ unsigned char mv[128];
  int bid = blockIdx.x;
  int c = bid & (NCHUNK-1);
  int h = (bid / NCHUNK) % NHEAD;
  int b = bid / (NCHUNK*NHEAD);
  int p = threadIdx.x;
  int s = c*WWIN + p;
  size_t qoff = ((size_t)(b*NS + s))*HIDN + h*DHEAD;
  // q row (pre-scaled)
  float qf[64];
  #pragma unroll
  for (int j=0;j<32;j++){
    float a, bb; unpack2(((const unsigned int*)(Q + qoff))[j], a, bb);
    qf[2*j] = a*0.125f; qf[2*j+1] = bb*0.125f;
  }
  // init with global key/value (row 0)
  size_t goff = ((size_t)(b*NS))*HIDN + h*DHEAD;
  float m, l, acc[64];
  {
    float sg = 0.f;
    #pragma unroll
    for (int j=0;j<32;j++){
      float a, bb; unpack2(((const unsigned int*)(KG + goff))[j], a, bb);
      sg += qf[2*j]*a + qf[2*j+1]*bb;
    }
    m = sg; l = 1.0f;
    #pragma unroll
    for (int j=0;j<32;j++){
      float a, bb; unpack2(((const unsigned int*)(VG + goff))[j], a, bb);
      acc[2*j] = a; acc[2*j+1] = bb;
    }
  }
  for (int t0=0; t0<3*WWIN; t0+=128){
    __syncthreads();
    { // stage 128 key rows of K and V
      int i = threadIdx.x >> 1, half = threadIdx.x & 1;
      int kp = (c-1)*WWIN + t0 + i;
      bool inr = (kp >= 0) && (kp < NS);
      size_t koff = ((size_t)(b*NS + (inr?kp:0)))*HIDN + h*DHEAD + half*32;
      const uint4* ks = (const uint4*)(Kp + koff);
      const uint4* vs = (const uint4*)(Vp + koff);
      uint4* kd = (uint4*)(Kt + i*64 + half*32);
      uint4* vd = (uint4*)(Vt + i*64 + half*32);
      #pragma unroll
      for (int j=0;j<4;j++){
        uint4 kv = {0,0,0,0}, vv = {0,0,0,0};
        if (inr){ kv = ks[j]; vv = vs[j]; }
        kd[j] = kv; vd[j] = vv;
      }
      if (half==0) mv[i] = (unsigned char)(inr && (kp >= 1) && (am[b*NS + (inr?kp:0)] > 0));
    }
    __syncthreads();
    for (int j0=0; j0<128; j0+=8){
      float sc[8];
      #pragma unroll
      for (int jj=0;jj<8;jj++){
        int kk = t0 + j0 + jj;
        int rel = kk - WWIN - p;
        bool valid = (mv[j0+jj] != 0) && (rel >= -WWIN) && (rel <= WWIN);
        float sv = 0.f;
        const unsigned int* kr = (const unsigned int*)(Kt + (j0+jj)*64);
        #pragma unroll
        for (int j=0;j<32;j++){
          float a, bb; unpack2(kr[j], a, bb);
          sv += qf[2*j]*a + qf[2*j+1]*bb;
        }
        sc[jj] = valid ? sv : -1e9f;
      }
      float tm = sc[0];
      #pragma unroll
      for (int jj=1;jj<8;jj++) tm = fmaxf(tm, sc[jj]);
      float nm = fmaxf(m, tm);
      float alpha = __expf(m - nm);
      l *= alpha;
      #pragma unroll
      for (int d=0; d<64; d++) acc[d] *= alpha;
      m = nm;
      #pragma unroll
      for (int jj=0;jj<8;jj++){
        float w = __expf(sc[jj] - m);
        l += w;
        const unsigned int* vr = (const unsigned int*)(Vt + (j0+jj)*64);
        #pragma unroll
        for (int j=0;j<32;j++){
          float a, bb; unpack2(vr[j], a, bb);
          acc[2*j] += w*a; acc[2*j+1] += w*bb;
        }
      }
    }
  }
  float inv = 1.0f / l;
  #pragma unroll
  for (int j=0;j<32;j++){
    unsigned int lo = f2bf(acc[2*j]*inv);
    unsigned int hi = f2bf(acc[2*j+1]*inv);
    ((unsigned int*)(Out + qoff))[j] = lo | (hi<<16);
  }
}

// ---------------- global (CLS) query full attention, overwrites row 0 ----------------
__global__ __launch_bounds__(256) void global_attn(
    const unsigned short* __restrict__ QG, const unsigned short* __restrict__ KG,
    const unsigned short* __restrict__ VG, const int* __restrict__ am,
    unsigned short* __restrict__ Out){
  __shared__ float sc[NS];
  __shared__ float red[256];
  __shared__ float qs[64];
  __shared__ float outv[256];
  int t = threadIdx.x;
  int h = blockIdx.x % NHEAD, b = blockIdx.x / NHEAD;
  size_t base = ((size_t)(b*NS))*HIDN + h*DHEAD;
  if (t < 32){
    float a, bb; unpack2(((const unsigned int*)(QG + base))[t], a, bb);
    qs[2*t] = a*0.125f; qs[2*t+1] = bb*0.125f;
  }
  __syncthreads();
  for (int si = t; si < NS; si += 256){
    const unsigned int* kr = (const unsigned int*)(KG + ((size_t)(b*NS+si))*HIDN + h*DHEAD);
    float sv = 0.f;
    #pragma unroll 8
    for (int j=0;j<32;j++){ float a, bb; unpack2(kr[j], a, bb); sv += qs[2*j]*a + qs[2*j+1]*bb; }
    sc[si] = (am[b*NS+si] > 0) ? sv : -1e9f;
  }
  __syncthreads();
  float lm = -1e30f;
  for (int si=t; si<NS; si+=256) lm = fmaxf(lm, sc[si]);
  red[t] = lm; __syncthreads();
  for (int st=128; st>0; st>>=1){ if(t<st) red[t]=fmaxf(red[t],red[t+st]); __syncthreads(); }
  float mx = red[0]; __syncthreads();
  float ls = 0.f;
  for (int si=t; si<NS; si+=256){ float e = __expf(sc[si]-mx); sc[si]=e; ls += e; }
  red[t] = ls; __syncthreads();
  for (int st=128; st>0; st>>=1){ if(t<st) red[t]+=red[t+st]; __syncthreads(); }
  float denom = red[0];
  int d = t & 63, g = t >> 6;
  float pa = 0.f;
  for (int si=g; si<NS; si+=4)
    pa += sc[si] * bf2f(VG[((size_t)(b*NS+si))*HIDN + h*DHEAD + d]);
  outv[t] = pa; __syncthreads();
  if (t < 64){
    float o = (outv[t] + outv[64+t] + outv[128+t] + outv[192+t]) / denom;
    Out[base + t] = f2bf(o);
  }
}

// ---------------- classification head on CLS token (all fp32) ----------------
__global__ __launch_bounds__(256) void head_k(const float* __restrict__ X,
    const float* __restrict__ HW, const float* __restrict__ HB,
    float* __restrict__ Outp){
  int n = blockIdx.x*256 + threadIdx.x;
  int b = blockIdx.y;
  if (n >= NLABEL) return;
  const float* x0 = X + (size_t)b*NS*HIDN;
  float a = HB[n];
  #pragma unroll 8
  for (int d=0; d<HIDN; d++) a += x0[d] * HW[(size_t)d*NLABEL + n];
  Outp[(size_t)b*NLABEL + n] = a;
}

extern "C" void kernel_launch(void* const* d_in, const int* in_sizes, int n_in,
                              void* d_out, int out_size, void* d_ws, size_t ws_size,
                              hipStream_t stream){
  (void)in_sizes; (void)n_in; (void)out_size; (void)ws_size;
  const int* ids = (const int*)d_in[0];
  const int* am  = (const int*)d_in[1];
  const float* we  = (const float*)d_in[2];
  const float* pe  = (const float*)d_in[3];
  const float* elns= (const float*)d_in[4];
  const float* elnb= (const float*)d_in[5];
  const float* Wq  = (const float*)d_in[6];
  const float* bq  = (const float*)d_in[7];
  const float* Wk  = (const float*)d_in[8];
  const float* bk  = (const float*)d_in[9];
  const float* Wv  = (const float*)d_in[10];
  const float* bv  = (const float*)d_in[11];
  const float* Wqg = (const float*)d_in[12];
  const float* bqg = (const float*)d_in[13];
  const float* Wkg = (const float*)d_in[14];
  const float* bkg = (const float*)d_in[15];
  const float* Wvg = (const float*)d_in[16];
  const float* bvg = (const float*)d_in[17];
  const float* Wo  = (const float*)d_in[18];
  const float* bo  = (const float*)d_in[19];
  const float* l1s = (const float*)d_in[20];
  const float* l1b = (const float*)d_in[21];
  const float* W1  = (const float*)d_in[22];
  const float* b1  = (const float*)d_in[23];
  const float* W2  = (const float*)d_in[24];
  const float* b2  = (const float*)d_in[25];
  const float* l2s = (const float*)d_in[26];
  const float* l2b = (const float*)d_in[27];
  const float* hW  = (const float*)d_in[28];
  const float* hB  = (const float*)d_in[29];

  char* ws = (char*)d_ws;
  float* x = (float*)ws;                                    // 25,165,824 B
  float* y = (float*)(ws + 25165824);                       // 25,165,824 B
  unsigned short* xb = (unsigned short*)(ws + 50331648);    // 12,582,912 B
  unsigned short* qb = (unsigned short*)(ws + 62914560);
  unsigned short* kbuf = (unsigned short*)(ws + 75497472);
  unsigned short* vbuf = (unsigned short*)(ws + 88080384);
  unsigned short* qgb = (unsigned short*)(ws + 100663296);
  unsigned short* kgb = (unsigned short*)(ws + 113246208);
  unsigned short* vgb = (unsigned short*)(ws + 125829120);
  unsigned short* ao = (unsigned short*)(ws + 138412032);   // 12,582,912 B
  unsigned short* hbuf = (unsigned short*)(ws + 150994944); // 50,331,648 B
  unsigned short* wt = (unsigned short*)(ws + 201326592);   // 35,389,440 B

  const size_t SQ = 589824;        // 768*768
  const size_t SW = 2359296;       // 768*3072
  const size_t PERL = 7*SQ + 2*SW; // 8,847,360 elems per layer

  auto tr = [&](const float* src, unsigned short* dst, int R, int C){
    dim3 g(C/32, R/32), blk(32, 8);
    transpose_k<<<g, blk, 0, stream>>>(src, dst, R, C);
  };
  for (int l=0; l<NLAYER; l++){
    unsigned short* base = wt + (size_t)l*PERL;
    tr(Wq  + (size_t)l*SQ, base + 0*SQ, 768, 768);
    tr(Wk  + (size_t)l*SQ, base + 1*SQ, 768, 768);
    tr(Wv  + (size_t)l*SQ, base + 2*SQ, 768, 768);
    tr(Wqg + (size_t)l*SQ, base + 3*SQ, 768, 768);
    tr(Wkg + (size_t)l*SQ, base + 4*SQ, 768, 768);
    tr(Wvg + (size_t)l*SQ, base + 5*SQ, 768, 768);
    tr(Wo  + (size_t)l*SQ, base + 6*SQ, 768, 768);
    tr(W1  + (size_t)l*SW, base + 7*SQ, 768, 3072);
    tr(W2  + (size_t)l*SW, base + 7*SQ + SW, 3072, 768);
  }

  embed_k<<<(NBS*HIDN)/256, 256, 0, stream>>>(ids, we, pe, y);
  ln_k<<<NBS, 256, 0, stream>>>(y, nullptr, elns, elnb, x, xb);

  for (int l=0; l<NLAYER; l++){
    unsigned short* base = wt + (size_t)l*PERL;
    dim3 gp(12, 128);
    gemm_bt<0,0><<<gp, 256, 0, stream>>>(xb, base + 0*SQ, bq  + l*768, qb,   NBS, 768, 768);
    gemm_bt<0,0><<<gp, 256, 0, stream>>>(xb, base + 1*SQ, bk  + l*768, kbuf, NBS, 768, 768);
    gemm_bt<0,0><<<gp, 256, 0, stream>>>(xb, base + 2*SQ, bv  + l*768, vbuf, NBS, 768, 768);
    gemm_bt<0,0><<<gp, 256, 0, stream>>>(xb, base + 3*SQ, bqg + l*768, qgb,  NBS, 768, 768);
    gemm_bt<0,0><<<gp, 256, 0, stream>>>(xb, base + 4*SQ, bkg + l*768, kgb,  NBS, 768, 768);
    gemm_bt<0,0><<<gp, 256, 0, stream>>>(xb, base + 5*SQ, bvg + l*768, vgb,  NBS, 768, 768);
    band_attn<<<NB*NHEAD*NCHUNK, 256, 0, stream>>>(qb, kbuf, vbuf, kgb, vgb, am, ao);
    global_attn<<<NB*NHEAD, 256, 0, stream>>>(qgb, kgb, vgb, am, ao);
    gemm_bt<1,0><<<gp, 256, 0, stream>>>(ao, base + 6*SQ, bo + l*768, y, NBS, 768, 768);
    ln_k<<<NBS, 256, 0, stream>>>(y, x, l1s + l*768, l1b + l*768, x, xb);
    gemm_bt<0,1><<<dim3(48,128), 256, 0, stream>>>(xb, base + 7*SQ, b1 + l*3072, hbuf, NBS, 3072, 768);
    gemm_bt<1,0><<<dim3(12,128), 256, 0, stream>>>(hbuf, base + 7*SQ + SW, b2 + l*768, y, NBS, 768, 3072);
    ln_k<<<NBS, 256, 0, stream>>>(y, x, l2s + l*768, l2b + l*768, x, xb);
  }

  head_k<<<dim3((NLABEL+255)/256, NB), 256, 0, stream>>>(x, hW, hB, (float*)d_out);
}

// Round 3
// 1947.428 us; speedup vs baseline: 2.1492x; 2.1492x over previous
//
#include <hip/hip_runtime.h>
#include <hip/hip_bf16.h>
#include <math.h>

// ---- model dims ----
#define HIDN 768
#define NHEAD 12
#define DHEAD 64
#define WWIN 256
#define NCHUNK 16
#define NLAYER 2
#define FFND 3072
#define NLABEL 8921
#define NB 2
#define NS 4096
#define NBS (NB*NS)

typedef __attribute__((ext_vector_type(8))) short bf16x8;
typedef __attribute__((ext_vector_type(4))) float f32x4;
typedef unsigned short ushort_t;

__device__ __forceinline__ float bf2f(unsigned short u){
  union { unsigned int i; float f; } v; v.i = ((unsigned int)u) << 16; return v.f;
}
__device__ __forceinline__ unsigned short f2bf(float f){
  __hip_bfloat16 h = __float2bfloat16(f);
  return *reinterpret_cast<unsigned short*>(&h);
}
__device__ __forceinline__ void unpack2(unsigned int u, float& a, float& b){
  union { unsigned int i; float f; } x, y;
  x.i = u << 16; y.i = u & 0xffff0000u; a = x.f; b = y.f;
}

// DPP row-rotate helper: rotate within 16-lane row by N, combine for reductions.
#define DPP_ROR_F(x, N) __builtin_bit_cast(float, __builtin_amdgcn_update_dpp( \
    0, __builtin_bit_cast(int, (x)), 0x120 + (N), 0xf, 0xf, true))
__device__ __forceinline__ float rowmax16(float x){
  x = fmaxf(x, DPP_ROR_F(x, 1));
  x = fmaxf(x, DPP_ROR_F(x, 2));
  x = fmaxf(x, DPP_ROR_F(x, 4));
  x = fmaxf(x, DPP_ROR_F(x, 8));
  return x;
}
__device__ __forceinline__ float rowsum16(float x){
  x = x + DPP_ROR_F(x, 1);
  x = x + DPP_ROR_F(x, 2);
  x = x + DPP_ROR_F(x, 4);
  x = x + DPP_ROR_F(x, 8);
  return x;
}

// ---------------- embedding (fp32 inputs) ----------------
__global__ __launch_bounds__(256) void embed_k(const int* __restrict__ ids,
    const float* __restrict__ we, const float* __restrict__ pe,
    float* __restrict__ y){
  int i = blockIdx.x*256 + threadIdx.x;     // over NBS*HIDN exactly
  int row = i / HIDN; int d = i - row*HIDN;
  int s = row & (NS-1);
  int id = ids[row];
  y[i] = we[(size_t)id*HIDN + d] + pe[(size_t)s*HIDN + d];
}

// ---------------- layernorm (optional residual), fp32 + bf16 outputs ----------------
__global__ __launch_bounds__(256) void ln_k(const float* A, const float* R,
    const float* __restrict__ sc, const float* __restrict__ bi,
    float* X, unsigned short* XB){
  __shared__ float red[256];
  int row = blockIdx.x, t = threadIdx.x;
  size_t base = (size_t)row*HIDN;
  float v0 = A[base+t], v1 = A[base+t+256], v2 = A[base+t+512];
  if (R){ v0 += R[base+t]; v1 += R[base+t+256]; v2 += R[base+t+512]; }
  red[t] = v0+v1+v2; __syncthreads();
  for (int st=128; st>0; st>>=1){ if (t<st) red[t]+=red[t+st]; __syncthreads(); }
  float mean = red[0] * (1.0f/HIDN); __syncthreads();
  float d0=v0-mean, d1=v1-mean, d2=v2-mean;
  red[t] = d0*d0+d1*d1+d2*d2; __syncthreads();
  for (int st=128; st>0; st>>=1){ if (t<st) red[t]+=red[t+st]; __syncthreads(); }
  float rs = rsqrtf(red[0] * (1.0f/HIDN) + 1e-5f);
  float o0 = d0*rs*sc[t]     + bi[t];
  float o1 = d1*rs*sc[t+256] + bi[t+256];
  float o2 = d2*rs*sc[t+512] + bi[t+512];
  X[base+t]=o0; X[base+t+256]=o1; X[base+t+512]=o2;
  XB[base+t]=f2bf(o0); XB[base+t+256]=f2bf(o1); XB[base+t+512]=f2bf(o2);
}

// ---------------- fp32 [R,C] -> bf16 transpose [C,R] ----------------
__global__ __launch_bounds__(256) void transpose_k(const float* __restrict__ src,
    unsigned short* __restrict__ dst, int R, int C){
  __shared__ unsigned short tile[32][33];
  int ct = blockIdx.x*32, rt = blockIdx.y*32;
  int tx = threadIdx.x, ty = threadIdx.y;     // 32 x 8
  #pragma unroll
  for (int i=0;i<4;i++) tile[ty+i*8][tx] = f2bf(src[(size_t)(rt+ty+i*8)*C + ct + tx]);
  __syncthreads();
  #pragma unroll
  for (int i=0;i<4;i++) dst[(size_t)(ct+ty+i*8)*R + rt + tx] = tile[tx][ty+i*8];
}

// ---------------- GEMM: C[M,N] = A[M,K](bf16) * BT[N,K]^T (bf16) + bias(fp32) ----------------
template<int OUTF32, int GELU>
__global__ __launch_bounds__(256) void gemm_bt(const unsigned short* __restrict__ A,
    const unsigned short* __restrict__ BT, const float* __restrict__ bias,
    void* __restrict__ Cp, int M, int N, int K){
  __shared__ unsigned short As[64*32];
  __shared__ unsigned short Bs[64*32];
  int tid = threadIdx.x;
  int m0 = blockIdx.y*64, n0 = blockIdx.x*64;
  int r = tid >> 2, kc = (tid & 3) * 8;
  int lane = tid & 63, wid = tid >> 6;
  int waveM = (wid>>1)*32, waveN = (wid&1)*32;
  int m16 = lane & 15, quad = lane >> 4;
  f32x4 acc[2][2] = {};
  for (int kb=0; kb<K; kb+=32){
    uint4 av = *(const uint4*)(A  + (size_t)(m0+r)*K + kb + kc);
    uint4 bv = *(const uint4*)(BT + (size_t)(n0+r)*K + kb + kc);
    *(uint4*)(As + r*32 + kc) = av;
    *(uint4*)(Bs + r*32 + kc) = bv;
    __syncthreads();
    bf16x8 a0 = *(const bf16x8*)(As + (waveM + m16)*32 + quad*8);
    bf16x8 a1 = *(const bf16x8*)(As + (waveM + 16 + m16)*32 + quad*8);
    bf16x8 b0 = *(const bf16x8*)(Bs + (waveN + m16)*32 + quad*8);
    bf16x8 b1 = *(const bf16x8*)(Bs + (waveN + 16 + m16)*32 + quad*8);
    acc[0][0] = __builtin_amdgcn_mfma_f32_16x16x32_bf16(a0, b0, acc[0][0], 0,0,0);
    acc[0][1] = __builtin_amdgcn_mfma_f32_16x16x32_bf16(a0, b1, acc[0][1], 0,0,0);
    acc[1][0] = __builtin_amdgcn_mfma_f32_16x16x32_bf16(a1, b0, acc[1][0], 0,0,0);
    acc[1][1] = __builtin_amdgcn_mfma_f32_16x16x32_bf16(a1, b1, acc[1][1], 0,0,0);
    __syncthreads();
  }
  #pragma unroll
  for (int mi=0; mi<2; mi++)
  #pragma unroll
  for (int ni=0; ni<2; ni++){
    #pragma unroll
    for (int rg=0; rg<4; rg++){
      int row = m0 + waveM + mi*16 + quad*4 + rg;
      int col = n0 + waveN + ni*16 + m16;
      float v = acc[mi][ni][rg] + bias[col];
      if (GELU) v = 0.5f*v*(1.0f + erff(v*0.70710678118f));
      if (OUTF32) ((float*)Cp)[(size_t)row*N + col] = v;
      else ((unsigned short*)Cp)[(size_t)row*N + col] = f2bf(v);
    }
  }
}

// ---------------- MFMA banded sliding-window attention (+ global key column) ----------------
// Block = (b, h, chunk c): 4 waves x 64 queries. KV tiles of 64 keys, 12 tiles.
// S = Q*K^T via 16x16x32 MFMA; online softmax in C-layout (row=q=quad*4+rg, col=lane&15);
// P transposed through per-wave LDS (stride 72); V staged transposed so PV B-frags are b128.
__global__ __launch_bounds__(256, 2) void band_attn_mfma(
    const unsigned short* __restrict__ Q, const unsigned short* __restrict__ Kp,
    const unsigned short* __restrict__ Vp, const unsigned short* __restrict__ KG,
    const unsigned short* __restrict__ VG, const int* __restrict__ am,
    unsigned short* __restrict__ Out){
  __shared__ unsigned short Kt[64*72];        // [key][dim], pad 72
  __shared__ unsigned short Vt[64*72];        // [dim][key], pad 72 (transposed)
  __shared__ unsigned short Pbuf[4*64*72];    // per-wave P tile [q][key], pad 72
  __shared__ float mk[64];                    // per-key additive mask (0 / -1e9)
  __shared__ unsigned short kgs[64];
  __shared__ unsigned short vgs[64];

  const int tid = threadIdx.x;
  const int bid = blockIdx.x;
  const int c = bid & (NCHUNK-1);
  const int h = (bid / NCHUNK) % NHEAD;
  const int b = bid / (NCHUNK*NHEAD);
  const int lane = tid & 63, w = tid >> 6;
  const int n = lane & 15, quad = lane >> 4;
  const int qbase = w * 64;
  unsigned short* Pw = Pbuf + w*64*72;

  // stage kg/vg row (b, s=0, h)
  if (tid < 8)       ((uint4*)kgs)[tid]   = ((const uint4*)(KG + ((size_t)b*NS)*HIDN + h*DHEAD))[tid];
  else if (tid < 16) ((uint4*)vgs)[tid-8] = ((const uint4*)(VG + ((size_t)b*NS)*HIDN + h*DHEAD))[tid-8];
  __syncthreads();

  // Q A-frags (held in registers for the whole kernel)
  bf16x8 aQ[4][2];
  #pragma unroll
  for (int mi=0; mi<4; mi++)
  #pragma unroll
  for (int ks=0; ks<2; ks++)
    aQ[mi][ks] = *(const bf16x8*)(Q + ((size_t)(b*NS + c*WWIN + qbase + 16*mi + n))*HIDN
                                    + h*DHEAD + ks*32 + quad*8);

  // global CLS-key score per query via masked-B MFMA (col 0 = q . kg)
  f32x4 sacc[4] = {};
  #pragma unroll
  for (int ks=0; ks<2; ks++){
    bf16x8 bg = *(const bf16x8*)(kgs + ks*32 + quad*8);
    bf16x8 z8 = {};
    bg = (n == 0) ? bg : z8;
    #pragma unroll
    for (int mi=0; mi<4; mi++)
      sacc[mi] = __builtin_amdgcn_mfma_f32_16x16x32_bf16(aQ[mi][ks], bg, sacc[mi], 0,0,0);
  }
  float mst[4][4], lpt[4][4];
  f32x4 apv[4][4];
  float vgf[4];
  #pragma unroll
  for (int ni=0; ni<4; ni++) vgf[ni] = bf2f(vgs[16*ni + n]);
  #pragma unroll
  for (int mi=0; mi<4; mi++)
  #pragma unroll
  for (int rg=0; rg<4; rg++){
    float sg = __shfl(sacc[mi][rg], lane & 48);   // broadcast col-0 lane of this quad
    mst[mi][rg] = sg * 0.125f;
    lpt[mi][rg] = (n == 0) ? 1.0f : 0.0f;         // lane-partial row sum; global key weight=1
  }
  #pragma unroll
  for (int mi=0; mi<4; mi++)
  #pragma unroll
  for (int ni=0; ni<4; ni++)
  #pragma unroll
  for (int rg=0; rg<4; rg++) apv[mi][ni][rg] = vgf[ni];   // acc starts at vg * e^{sg-m}=1

  for (int t=0; t<12; t++){
    __syncthreads();
    { // stage 64 keys: K natural, V transposed; mask
      int i = tid >> 2, d0 = (tid & 3) * 8;
      int kp = (c-1)*WWIN + t*64 + i;
      int kpc = min(max(kp, 0), NS-1);
      size_t gb = ((size_t)(b*NS + kpc))*HIDN + h*DHEAD;
      uint4 k0 = *(const uint4*)(Kp + gb + d0);
      uint4 k1 = *(const uint4*)(Kp + gb + d0 + 32);
      uint4 v0 = *(const uint4*)(Vp + gb + d0);
      uint4 v1 = *(const uint4*)(Vp + gb + d0 + 32);
      *(uint4*)(Kt + i*72 + d0) = k0;
      *(uint4*)(Kt + i*72 + d0 + 32) = k1;
      const unsigned short* s0 = (const unsigned short*)&v0;
      const unsigned short* s1 = (const unsigned short*)&v1;
      #pragma unroll
      for (int j=0;j<8;j++){
        Vt[(d0+j)*72 + i] = s0[j];
        Vt[(d0+32+j)*72 + i] = s1[j];
      }
      if ((tid & 3) == 0)
        mk[i] = (kp >= 1 && kp < NS && am[b*NS + kpc] > 0) ? 0.0f : -1e9f;
    }
    __syncthreads();

    float mkv[4];
    #pragma unroll
    for (int ni=0; ni<4; ni++) mkv[ni] = mk[16*ni + n];

    // ---- QK^T ----
    f32x4 accs[4][4] = {};
    #pragma unroll
    for (int ks=0; ks<2; ks++){
      bf16x8 bK[4];
      #pragma unroll
      for (int ni=0; ni<4; ni++)
        bK[ni] = *(const bf16x8*)(Kt + (16*ni + n)*72 + ks*32 + quad*8);
      #pragma unroll
      for (int mi=0; mi<4; mi++)
      #pragma unroll
      for (int ni=0; ni<4; ni++)
        accs[mi][ni] = __builtin_amdgcn_mfma_f32_16x16x32_bf16(aQ[mi][ks], bK[ni], accs[mi][ni], 0,0,0);
    }

    // ---- online softmax (C-layout) + P write ----
    #pragma unroll
    for (int mi=0; mi<4; mi++){
      float sv[4][4];
      #pragma unroll
      for (int ni=0; ni<4; ni++)
      #pragma unroll
      for (int rg=0; rg<4; rg++){
        int kk = t*64 + 16*ni + n;                 // key pos in 3W window coords
        int pr = qbase + 16*mi + quad*4 + rg;      // query pos in chunk
        float s = accs[mi][ni][rg]*0.125f + mkv[ni];
        if ((unsigned)(kk - pr) > 512u) s = -1e9f; // band |kk-256-pr|<=256
        sv[ni][rg] = s;
      }
      #pragma unroll
      for (int rg=0; rg<4; rg++){
        float rm = fmaxf(fmaxf(sv[0][rg], sv[1][rg]), fmaxf(sv[2][rg], sv[3][rg]));
        rm = rowmax16(rm);
        float mold = mst[mi][rg];
        float mnew = fmaxf(mold, rm);
        float alpha = __expf(mold - mnew);
        mst[mi][rg] = mnew;
        float psum = 0.f;
        #pragma unroll
        for (int ni=0; ni<4; ni++){
          float pv = __expf(sv[ni][rg] - mnew);
          sv[ni][rg] = pv;
          psum += pv;
        }
        lpt[mi][rg] = lpt[mi][rg]*alpha + psum;
        #pragma unroll
        for (int ni=0; ni<4; ni++) apv[mi][ni][rg] *= alpha;
        int prow = 16*mi + quad*4 + rg;
        #pragma unroll
        for (int ni=0; ni<4; ni++)
          Pw[prow*72 + 16*ni + n] = f2bf(sv[ni][rg]);
      }
    }

    // ---- PV ----
    #pragma unroll
    for (int ks2=0; ks2<2; ks2++){
      bf16x8 aP[4], bV[4];
      #pragma unroll
      for (int mi=0; mi<4; mi++)
        aP[mi] = *(const bf16x8*)(Pw + (16*mi + n)*72 + ks2*32 + quad*8);
      #pragma unroll
      for (int ni=0; ni<4; ni++)
        bV[ni] = *(const bf16x8*)(Vt + (16*ni + n)*72 + ks2*32 + quad*8);
      #pragma unroll
      for (int mi=0; mi<4; mi++)
      #pragma unroll
      for (int ni=0; ni<4; ni++)
        apv[mi][ni] = __builtin_amdgcn_mfma_f32_16x16x32_bf16(aP[mi], bV[ni], apv[mi][ni], 0,0,0);
    }
  }

  // ---- finalize: l row-reduction, normalize, store ----
  #pragma unroll
  for (int mi=0; mi<4; mi++)
  #pragma unroll
  for (int rg=0; rg<4; rg++){
    float L = rowsum16(lpt[mi][rg]);
    float inv = 1.0f / L;
    int q = c*WWIN + qbase + 16*mi + quad*4 + rg;
    size_t ob = ((size_t)(b*NS + q))*HIDN + h*DHEAD;
    #pragma unroll
    for (int ni=0; ni<4; ni++)
      Out[ob + 16*ni + n] = f2bf(apv[mi][ni][rg] * inv);
  }
}

// ---------------- global (CLS) query full attention, overwrites row 0 ----------------
__global__ __launch_bounds__(256) void global_attn(
    const unsigned short* __restrict__ QG, const unsigned short* __restrict__ KG,
    const unsigned short* __restrict__ VG, const int* __restrict__ am,
    unsigned short* __restrict__ Out){
  __shared__ float sc[NS];
  __shared__ float red[256];
  __shared__ float qs[64];
  __shared__ float outv[256];
  int t = threadIdx.x;
  int h = blockIdx.x % NHEAD, b = blockIdx.x / NHEAD;
  size_t base = ((size_t)(b*NS))*HIDN + h*DHEAD;
  if (t < 32){
    float a, bb; unpack2(((const unsigned int*)(QG + base))[t], a, bb);
    qs[2*t] = a*0.125f; qs[2*t+1] = bb*0.125f;
  }
  __syncthreads();
  for (int si = t; si < NS; si += 256){
    const unsigned int* kr = (const unsigned int*)(KG + ((size_t)(b*NS+si))*HIDN + h*DHEAD);
    float sv = 0.f;
    #pragma unroll 8
    for (int j=0;j<32;j++){ float a, bb; unpack2(kr[j], a, bb); sv += qs[2*j]*a + qs[2*j+1]*bb; }
    sc[si] = (am[b*NS+si] > 0) ? sv : -1e9f;
  }
  __syncthreads();
  float lm = -1e30f;
  for (int si=t; si<NS; si+=256) lm = fmaxf(lm, sc[si]);
  red[t] = lm; __syncthreads();
  for (int st=128; st>0; st>>=1){ if(t<st) red[t]=fmaxf(red[t],red[t+st]); __syncthreads(); }
  float mx = red[0]; __syncthreads();
  float ls = 0.f;
  for (int si=t; si<NS; si+=256){ float e = __expf(sc[si]-mx); sc[si]=e; ls += e; }
  red[t] = ls; __syncthreads();
  for (int st=128; st>0; st>>=1){ if(t<st) red[t]+=red[t+st]; __syncthreads(); }
  float denom = red[0];
  int d = t & 63, g = t >> 6;
  float pa = 0.f;
  for (int si=g; si<NS; si+=4)
    pa += sc[si] * bf2f(VG[((size_t)(b*NS+si))*HIDN + h*DHEAD + d]);
  outv[t] = pa; __syncthreads();
  if (t < 64){
    float o = (outv[t] + outv[64+t] + outv[128+t] + outv[192+t]) / denom;
    Out[base + t] = f2bf(o);
  }
}

// ---------------- classification head on CLS token (all fp32) ----------------
__global__ __launch_bounds__(256) void head_k(const float* __restrict__ X,
    const float* __restrict__ HW, const float* __restrict__ HB,
    float* __restrict__ Outp){
  int n = blockIdx.x*256 + threadIdx.x;
  int b = blockIdx.y;
  if (n >= NLABEL) return;
  const float* x0 = X + (size_t)b*NS*HIDN;
  float a = HB[n];
  #pragma unroll 8
  for (int d=0; d<HIDN; d++) a += x0[d] * HW[(size_t)d*NLABEL + n];
  Outp[(size_t)b*NLABEL + n] = a;
}

extern "C" void kernel_launch(void* const* d_in, const int* in_sizes, int n_in,
                              void* d_out, int out_size, void* d_ws, size_t ws_size,
                              hipStream_t stream){
  (void)in_sizes; (void)n_in; (void)out_size; (void)ws_size;
  const int* ids = (const int*)d_in[0];
  const int* am  = (const int*)d_in[1];
  const float* we  = (const float*)d_in[2];
  const float* pe  = (const float*)d_in[3];
  const float* elns= (const float*)d_in[4];
  const float* elnb= (const float*)d_in[5];
  const float* Wq  = (const float*)d_in[6];
  const float* bq  = (const float*)d_in[7];
  const float* Wk  = (const float*)d_in[8];
  const float* bk  = (const float*)d_in[9];
  const float* Wv  = (const float*)d_in[10];
  const float* bv  = (const float*)d_in[11];
  const float* Wqg = (const float*)d_in[12];
  const float* bqg = (const float*)d_in[13];
  const float* Wkg = (const float*)d_in[14];
  const float* bkg = (const float*)d_in[15];
  const float* Wvg = (const float*)d_in[16];
  const float* bvg = (const float*)d_in[17];
  const float* Wo  = (const float*)d_in[18];
  const float* bo  = (const float*)d_in[19];
  const float* l1s = (const float*)d_in[20];
  const float* l1b = (const float*)d_in[21];
  const float* W1  = (const float*)d_in[22];
  const float* b1  = (const float*)d_in[23];
  const float* W2  = (const float*)d_in[24];
  const float* b2  = (const float*)d_in[25];
  const float* l2s = (const float*)d_in[26];
  const float* l2b = (const float*)d_in[27];
  const float* hW  = (const float*)d_in[28];
  const float* hB  = (const float*)d_in[29];

  char* ws = (char*)d_ws;
  float* x = (float*)ws;                                    // 25,165,824 B
  float* y = (float*)(ws + 25165824);                       // 25,165,824 B
  unsigned short* xb = (unsigned short*)(ws + 50331648);    // 12,582,912 B
  unsigned short* qb = (unsigned short*)(ws + 62914560);
  unsigned short* kbuf = (unsigned short*)(ws + 75497472);
  unsigned short* vbuf = (unsigned short*)(ws + 88080384);
  unsigned short* qgb = (unsigned short*)(ws + 100663296);
  unsigned short* kgb = (unsigned short*)(ws + 113246208);
  unsigned short* vgb = (unsigned short*)(ws + 125829120);
  unsigned short* ao = (unsigned short*)(ws + 138412032);   // 12,582,912 B
  unsigned short* hbuf = (unsigned short*)(ws + 150994944); // 50,331,648 B
  unsigned short* wt = (unsigned short*)(ws + 201326592);   // 35,389,440 B

  const size_t SQ = 589824;        // 768*768
  const size_t SW = 2359296;       // 768*3072
  const size_t PERL = 7*SQ + 2*SW; // 8,847,360 elems per layer

  auto tr = [&](const float* src, unsigned short* dst, int R, int C){
    dim3 g(C/32, R/32), blk(32, 8);
    transpose_k<<<g, blk, 0, stream>>>(src, dst, R, C);
  };
  for (int l=0; l<NLAYER; l++){
    unsigned short* base = wt + (size_t)l*PERL;
    tr(Wq  + (size_t)l*SQ, base + 0*SQ, 768, 768);
    tr(Wk  + (size_t)l*SQ, base + 1*SQ, 768, 768);
    tr(Wv  + (size_t)l*SQ, base + 2*SQ, 768, 768);
    tr(Wqg + (size_t)l*SQ, base + 3*SQ, 768, 768);
    tr(Wkg + (size_t)l*SQ, base + 4*SQ, 768, 768);
    tr(Wvg + (size_t)l*SQ, base + 5*SQ, 768, 768);
    tr(Wo  + (size_t)l*SQ, base + 6*SQ, 768, 768);
    tr(W1  + (size_t)l*SW, base + 7*SQ, 768, 3072);
    tr(W2  + (size_t)l*SW, base + 7*SQ + SW, 3072, 768);
  }

  embed_k<<<(NBS*HIDN)/256, 256, 0, stream>>>(ids, we, pe, y);
  ln_k<<<NBS, 256, 0, stream>>>(y, nullptr, elns, elnb, x, xb);

  for (int l=0; l<NLAYER; l++){
    unsigned short* base = wt + (size_t)l*PERL;
    dim3 gp(12, 128);
    gemm_bt<0,0><<<gp, 256, 0, stream>>>(xb, base + 0*SQ, bq  + l*768, qb,   NBS, 768, 768);
    gemm_bt<0,0><<<gp, 256, 0, stream>>>(xb, base + 1*SQ, bk  + l*768, kbuf, NBS, 768, 768);
    gemm_bt<0,0><<<gp, 256, 0, stream>>>(xb, base + 2*SQ, bv  + l*768, vbuf, NBS, 768, 768);
    gemm_bt<0,0><<<gp, 256, 0, stream>>>(xb, base + 3*SQ, bqg + l*768, qgb,  NBS, 768, 768);
    gemm_bt<0,0><<<gp, 256, 0, stream>>>(xb, base + 4*SQ, bkg + l*768, kgb,  NBS, 768, 768);
    gemm_bt<0,0><<<gp, 256, 0, stream>>>(xb, base + 5*SQ, bvg + l*768, vgb,  NBS, 768, 768);
    band_attn_mfma<<<NB*NHEAD*NCHUNK, 256, 0, stream>>>(qb, kbuf, vbuf, kgb, vgb, am, ao);
    global_attn<<<NB*NHEAD, 256, 0, stream>>>(qgb, kgb, vgb, am, ao);
    gemm_bt<1,0><<<gp, 256, 0, stream>>>(ao, base + 6*SQ, bo + l*768, y, NBS, 768, 768);
    ln_k<<<NBS, 256, 0, stream>>>(y, x, l1s + l*768, l1b + l*768, x, xb);
    gemm_bt<0,1><<<dim3(48,128), 256, 0, stream>>>(xb, base + 7*SQ, b1 + l*3072, hbuf, NBS, 3072, 768);
    gemm_bt<1,0><<<dim3(12,128), 256, 0, stream>>>(hbuf, base + 7*SQ + SW, b2 + l*768, y, NBS, 768, 3072);
    ln_k<<<NBS, 256, 0, stream>>>(y, x, l2s + l*768, l2b + l*768, x, xb);
  }

  head_k<<<dim3((NLABEL+255)/256, NB), 256, 0, stream>>>(x, hW, hB, (float*)d_out);
}

// Round 4
// 1256.119 us; speedup vs baseline: 3.3321x; 1.5504x over previous
//
#include <hip/hip_runtime.h>
#include <hip/hip_bf16.h>
#include <math.h>

// ---- model dims ----
#define HIDN 768
#define NHEAD 12
#define DHEAD 64
#define WWIN 256
#define NCHUNK 16
#define NLAYER 2
#define FFND 3072
#define NLABEL 8921
#define NB 2
#define NS 4096
#define NBS (NB*NS)

typedef __attribute__((ext_vector_type(8))) short bf16x8;
typedef __attribute__((ext_vector_type(4))) float f32x4;

__device__ __forceinline__ float bf2f(unsigned short u){
  union { unsigned int i; float f; } v; v.i = ((unsigned int)u) << 16; return v.f;
}
__device__ __forceinline__ unsigned short f2bf(float f){
  __hip_bfloat16 h = __float2bfloat16(f);
  return *reinterpret_cast<unsigned short*>(&h);
}
__device__ __forceinline__ void unpack2(unsigned int u, float& a, float& b){
  union { unsigned int i; float f; } x, y;
  x.i = u << 16; y.i = u & 0xffff0000u; a = x.f; b = y.f;
}
// async global->LDS, 16B per lane; LDS dest = ldsbase + lane*16
__device__ __forceinline__ void gld_lds16(const unsigned short* g, unsigned short* l){
  __builtin_amdgcn_global_load_lds((const __attribute__((address_space(1))) unsigned int*)g,
                                   (__attribute__((address_space(3))) unsigned int*)l, 16, 0, 0);
}

// DPP row-rotate helper: rotate within 16-lane row by N, combine for reductions.
#define DPP_ROR_F(x, N) __builtin_bit_cast(float, __builtin_amdgcn_update_dpp( \
    0, __builtin_bit_cast(int, (x)), 0x120 + (N), 0xf, 0xf, true))
__device__ __forceinline__ float rowmax16(float x){
  x = fmaxf(x, DPP_ROR_F(x, 1));
  x = fmaxf(x, DPP_ROR_F(x, 2));
  x = fmaxf(x, DPP_ROR_F(x, 4));
  x = fmaxf(x, DPP_ROR_F(x, 8));
  return x;
}
__device__ __forceinline__ float rowsum16(float x){
  x = x + DPP_ROR_F(x, 1);
  x = x + DPP_ROR_F(x, 2);
  x = x + DPP_ROR_F(x, 4);
  x = x + DPP_ROR_F(x, 8);
  return x;
}

// ---------------- embedding (fp32 inputs) ----------------
__global__ __launch_bounds__(256) void embed_k(const int* __restrict__ ids,
    const float* __restrict__ we, const float* __restrict__ pe,
    float* __restrict__ y){
  int i = blockIdx.x*256 + threadIdx.x;
  int row = i / HIDN; int d = i - row*HIDN;
  int s = row & (NS-1);
  int id = ids[row];
  y[i] = we[(size_t)id*HIDN + d] + pe[(size_t)s*HIDN + d];
}

// ---------------- layernorm (optional residual), fp32 + bf16 outputs ----------------
__global__ __launch_bounds__(256) void ln_k(const float* A, const float* R,
    const float* __restrict__ sc, const float* __restrict__ bi,
    float* X, unsigned short* XB){
  __shared__ float red[256];
  int row = blockIdx.x, t = threadIdx.x;
  size_t base = (size_t)row*HIDN;
  float v0 = A[base+t], v1 = A[base+t+256], v2 = A[base+t+512];
  if (R){ v0 += R[base+t]; v1 += R[base+t+256]; v2 += R[base+t+512]; }
  red[t] = v0+v1+v2; __syncthreads();
  for (int st=128; st>0; st>>=1){ if (t<st) red[t]+=red[t+st]; __syncthreads(); }
  float mean = red[0] * (1.0f/HIDN); __syncthreads();
  float d0=v0-mean, d1=v1-mean, d2=v2-mean;
  red[t] = d0*d0+d1*d1+d2*d2; __syncthreads();
  for (int st=128; st>0; st>>=1){ if (t<st) red[t]+=red[t+st]; __syncthreads(); }
  float rs = rsqrtf(red[0] * (1.0f/HIDN) + 1e-5f);
  float o0 = d0*rs*sc[t]     + bi[t];
  float o1 = d1*rs*sc[t+256] + bi[t+256];
  float o2 = d2*rs*sc[t+512] + bi[t+512];
  X[base+t]=o0; X[base+t+256]=o1; X[base+t+512]=o2;
  XB[base+t]=f2bf(o0); XB[base+t+256]=f2bf(o1); XB[base+t+512]=f2bf(o2);
}

// ---------------- fp32 [R,C] -> bf16 transpose [C,R] ----------------
__global__ __launch_bounds__(256) void transpose_k(const float* __restrict__ src,
    unsigned short* __restrict__ dst, int R, int C){
  __shared__ unsigned short tile[32][33];
  int ct = blockIdx.x*32, rt = blockIdx.y*32;
  int tx = threadIdx.x, ty = threadIdx.y;     // 32 x 8
  #pragma unroll
  for (int i=0;i<4;i++) tile[ty+i*8][tx] = f2bf(src[(size_t)(rt+ty+i*8)*C + ct + tx]);
  __syncthreads();
  #pragma unroll
  for (int i=0;i<4;i++) dst[(size_t)(ct+ty+i*8)*R + rt + tx] = tile[tx][ty+i*8];
}

// ---------------- GEMM 128x128xBK64, global_load_lds staging, XOR-swizzled LDS ----
// C[M,N] = A[M,K](bf16) * BT[N,K]^T (bf16) + bias(fp32). M%128==0, N%128==0, K%64==0.
// LDS layout: element (row r, k-chunk q of 8 shorts) at row*64 + (q ^ (r&7))*8.
template<int OUTF32, int GELU>
__global__ __launch_bounds__(256) void gemm128(const unsigned short* __restrict__ A,
    const unsigned short* __restrict__ BT, const float* __restrict__ bias,
    void* __restrict__ Cp, int M, int N, int K){
  __shared__ unsigned short As[128*64];
  __shared__ unsigned short Bs[128*64];
  const int tid = threadIdx.x;
  const int m0 = blockIdx.y*128, n0 = blockIdx.x*128;
  const int lane = tid & 63, w = tid >> 6;
  const int n = lane & 15, quad = lane >> 4;
  const int wm = (w>>1)*64, wn = (w&1)*64;
  const int lr = lane >> 3, site = lane & 7;   // staging: 8 rows x 8 sites per instr
  f32x4 acc[4][4] = {};
  for (int kb=0; kb<K; kb+=64){
    #pragma unroll
    for (int j=0;j<4;j++){
      int rbase = w*32 + j*8;
      int r = rbase + lr;
      int q = site ^ (r & 7);
      gld_lds16(A  + (size_t)(m0+r)*K + kb + q*8, &As[rbase*64]);
      gld_lds16(BT + (size_t)(n0+r)*K + kb + q*8, &Bs[rbase*64]);
    }
    __syncthreads();
    #pragma unroll
    for (int ks=0; ks<2; ks++){
      bf16x8 a[4], b[4];
      #pragma unroll
      for (int i=0;i<4;i++){
        int rm = wm + i*16 + n;
        a[i] = *(const bf16x8*)&As[rm*64 + (((ks*4+quad) ^ (rm&7))<<3)];
        int rn = wn + i*16 + n;
        b[i] = *(const bf16x8*)&Bs[rn*64 + (((ks*4+quad) ^ (rn&7))<<3)];
      }
      #pragma unroll
      for (int mi=0;mi<4;mi++)
      #pragma unroll
      for (int ni=0;ni<4;ni++)
        acc[mi][ni] = __builtin_amdgcn_mfma_f32_16x16x32_bf16(a[mi], b[ni], acc[mi][ni], 0,0,0);
    }
    __syncthreads();
  }
  #pragma unroll
  for (int mi=0; mi<4; mi++)
  #pragma unroll
  for (int ni=0; ni<4; ni++){
    int col = n0 + wn + ni*16 + n;
    float bsv = bias[col];
    #pragma unroll
    for (int rg=0; rg<4; rg++){
      int row = m0 + wm + mi*16 + quad*4 + rg;
      float v = acc[mi][ni][rg] + bsv;
      if (GELU) v = 0.5f*v*(1.0f + erff(v*0.70710678118f));
      if (OUTF32) ((float*)Cp)[(size_t)row*N + col] = v;
      else ((unsigned short*)Cp)[(size_t)row*N + col] = f2bf(v);
    }
  }
}

// ---------------- MFMA banded sliding-window attention (+ global key column) ----------------
__global__ __launch_bounds__(256, 2) void band_attn_mfma(
    const unsigned short* __restrict__ Q, const unsigned short* __restrict__ Kp,
    const unsigned short* __restrict__ Vp, const unsigned short* __restrict__ KG,
    const unsigned short* __restrict__ VG, const int* __restrict__ am,
    unsigned short* __restrict__ Out){
  __shared__ unsigned short Kt[64*72];        // [key][dim], pad 72
  __shared__ unsigned short Vt[64*72];        // [dim][key], pad 72 (transposed)
  __shared__ unsigned short Pbuf[4*64*72];    // per-wave P tile [q][key], pad 72
  __shared__ float mk[64];                    // per-key additive mask (0 / -1e9)
  __shared__ unsigned short kgs[64];
  __shared__ unsigned short vgs[64];

  const int tid = threadIdx.x;
  const int bid = blockIdx.x;
  const int c = bid & (NCHUNK-1);
  const int h = (bid / NCHUNK) % NHEAD;
  const int b = bid / (NCHUNK*NHEAD);
  const int lane = tid & 63, w = tid >> 6;
  const int n = lane & 15, quad = lane >> 4;
  const int qbase = w * 64;
  unsigned short* Pw = Pbuf + w*64*72;

  if (tid < 8)       ((uint4*)kgs)[tid]   = ((const uint4*)(KG + ((size_t)b*NS)*HIDN + h*DHEAD))[tid];
  else if (tid < 16) ((uint4*)vgs)[tid-8] = ((const uint4*)(VG + ((size_t)b*NS)*HIDN + h*DHEAD))[tid-8];
  __syncthreads();

  bf16x8 aQ[4][2];
  #pragma unroll
  for (int mi=0; mi<4; mi++)
  #pragma unroll
  for (int ks=0; ks<2; ks++)
    aQ[mi][ks] = *(const bf16x8*)(Q + ((size_t)(b*NS + c*WWIN + qbase + 16*mi + n))*HIDN
                                    + h*DHEAD + ks*32 + quad*8);

  f32x4 sacc[4] = {};
  #pragma unroll
  for (int ks=0; ks<2; ks++){
    bf16x8 bg = *(const bf16x8*)(kgs + ks*32 + quad*8);
    bf16x8 z8 = {};
    bg = (n == 0) ? bg : z8;
    #pragma unroll
    for (int mi=0; mi<4; mi++)
      sacc[mi] = __builtin_amdgcn_mfma_f32_16x16x32_bf16(aQ[mi][ks], bg, sacc[mi], 0,0,0);
  }
  float mst[4][4], lpt[4][4];
  f32x4 apv[4][4];
  float vgf[4];
  #pragma unroll
  for (int ni=0; ni<4; ni++) vgf[ni] = bf2f(vgs[16*ni + n]);
  #pragma unroll
  for (int mi=0; mi<4; mi++)
  #pragma unroll
  for (int rg=0; rg<4; rg++){
    float sg = __shfl(sacc[mi][rg], lane & 48);
    mst[mi][rg] = sg * 0.125f;
    lpt[mi][rg] = (n == 0) ? 1.0f : 0.0f;
  }
  #pragma unroll
  for (int mi=0; mi<4; mi++)
  #pragma unroll
  for (int ni=0; ni<4; ni++)
  #pragma unroll
  for (int rg=0; rg<4; rg++) apv[mi][ni][rg] = vgf[ni];

  for (int t=0; t<12; t++){
    __syncthreads();
    {
      int i = tid >> 2, d0 = (tid & 3) * 8;
      int kp = (c-1)*WWIN + t*64 + i;
      int kpc = min(max(kp, 0), NS-1);
      size_t gb = ((size_t)(b*NS + kpc))*HIDN + h*DHEAD;
      uint4 k0 = *(const uint4*)(Kp + gb + d0);
      uint4 k1 = *(const uint4*)(Kp + gb + d0 + 32);
      uint4 v0 = *(const uint4*)(Vp + gb + d0);
      uint4 v1 = *(const uint4*)(Vp + gb + d0 + 32);
      *(uint4*)(Kt + i*72 + d0) = k0;
      *(uint4*)(Kt + i*72 + d0 + 32) = k1;
      const unsigned short* s0 = (const unsigned short*)&v0;
      const unsigned short* s1 = (const unsigned short*)&v1;
      #pragma unroll
      for (int j=0;j<8;j++){
        Vt[(d0+j)*72 + i] = s0[j];
        Vt[(d0+32+j)*72 + i] = s1[j];
      }
      if ((tid & 3) == 0)
        mk[i] = (kp >= 1 && kp < NS && am[b*NS + kpc] > 0) ? 0.0f : -1e9f;
    }
    __syncthreads();

    float mkv[4];
    #pragma unroll
    for (int ni=0; ni<4; ni++) mkv[ni] = mk[16*ni + n];

    f32x4 accs[4][4] = {};
    #pragma unroll
    for (int ks=0; ks<2; ks++){
      bf16x8 bK[4];
      #pragma unroll
      for (int ni=0; ni<4; ni++)
        bK[ni] = *(const bf16x8*)(Kt + (16*ni + n)*72 + ks*32 + quad*8);
      #pragma unroll
      for (int mi=0; mi<4; mi++)
      #pragma unroll
      for (int ni=0; ni<4; ni++)
        accs[mi][ni] = __builtin_amdgcn_mfma_f32_16x16x32_bf16(aQ[mi][ks], bK[ni], accs[mi][ni], 0,0,0);
    }

    #pragma unroll
    for (int mi=0; mi<4; mi++){
      float sv[4][4];
      #pragma unroll
      for (int ni=0; ni<4; ni++)
      #pragma unroll
      for (int rg=0; rg<4; rg++){
        int kk = t*64 + 16*ni + n;
        int pr = qbase + 16*mi + quad*4 + rg;
        float s = accs[mi][ni][rg]*0.125f + mkv[ni];
        if ((unsigned)(kk - pr) > 512u) s = -1e9f;
        sv[ni][rg] = s;
      }
      #pragma unroll
      for (int rg=0; rg<4; rg++){
        float rm = fmaxf(fmaxf(sv[0][rg], sv[1][rg]), fmaxf(sv[2][rg], sv[3][rg]));
        rm = rowmax16(rm);
        float mold = mst[mi][rg];
        float mnew = fmaxf(mold, rm);
        float alpha = __expf(mold - mnew);
        mst[mi][rg] = mnew;
        float psum = 0.f;
        #pragma unroll
        for (int ni=0; ni<4; ni++){
          float pv = __expf(sv[ni][rg] - mnew);
          sv[ni][rg] = pv;
          psum += pv;
        }
        lpt[mi][rg] = lpt[mi][rg]*alpha + psum;
        #pragma unroll
        for (int ni=0; ni<4; ni++) apv[mi][ni][rg] *= alpha;
        int prow = 16*mi + quad*4 + rg;
        #pragma unroll
        for (int ni=0; ni<4; ni++)
          Pw[prow*72 + 16*ni + n] = f2bf(sv[ni][rg]);
      }
    }

    #pragma unroll
    for (int ks2=0; ks2<2; ks2++){
      bf16x8 aP[4], bV[4];
      #pragma unroll
      for (int mi=0; mi<4; mi++)
        aP[mi] = *(const bf16x8*)(Pw + (16*mi + n)*72 + ks2*32 + quad*8);
      #pragma unroll
      for (int ni=0; ni<4; ni++)
        bV[ni] = *(const bf16x8*)(Vt + (16*ni + n)*72 + ks2*32 + quad*8);
      #pragma unroll
      for (int mi=0; mi<4; mi++)
      #pragma unroll
      for (int ni=0; ni<4; ni++)
        apv[mi][ni] = __builtin_amdgcn_mfma_f32_16x16x32_bf16(aP[mi], bV[ni], apv[mi][ni], 0,0,0);
    }
  }

  #pragma unroll
  for (int mi=0; mi<4; mi++)
  #pragma unroll
  for (int rg=0; rg<4; rg++){
    float L = rowsum16(lpt[mi][rg]);
    float inv = 1.0f / L;
    int q = c*WWIN + qbase + 16*mi + quad*4 + rg;
    size_t ob = ((size_t)(b*NS + q))*HIDN + h*DHEAD;
    #pragma unroll
    for (int ni=0; ni<4; ni++)
      Out[ob + 16*ni + n] = f2bf(apv[mi][ni][rg] * inv);
  }
}

// ---------------- split-flash global (CLS) attention: partials over 128-key chunks ----
__global__ __launch_bounds__(128) void gattn_part(
    const unsigned short* __restrict__ QG0, const unsigned short* __restrict__ KG,
    const unsigned short* __restrict__ VG, const int* __restrict__ am,
    float* __restrict__ part){
  __shared__ float qs[64];
  __shared__ float ps[128];
  __shared__ float red[128];
  int t = threadIdx.x;
  int cx = blockIdx.x, h = blockIdx.y, b = blockIdx.z;
  if (t < 32){
    float a, bb; unpack2(((const unsigned int*)(QG0 + (size_t)b*128*HIDN + h*DHEAD))[t], a, bb);
    qs[2*t]=a*0.125f; qs[2*t+1]=bb*0.125f;
  }
  __syncthreads();
  int kp = cx*128 + t;
  const unsigned int* kr = (const unsigned int*)(KG + ((size_t)(b*NS+kp))*HIDN + h*DHEAD);
  float sv = 0.f;
  #pragma unroll
  for (int j=0;j<32;j++){ float a,bb; unpack2(kr[j],a,bb); sv += qs[2*j]*a + qs[2*j+1]*bb; }
  if (am[b*NS+kp] <= 0) sv = -1e9f;
  red[t] = sv; __syncthreads();
  for (int st=64; st>0; st>>=1){ if (t<st) red[t] = fmaxf(red[t], red[t+st]); __syncthreads(); }
  float M = red[0]; __syncthreads();
  float e = __expf(sv - M);
  ps[t] = e; red[t] = e; __syncthreads();
  for (int st=64; st>0; st>>=1){ if (t<st) red[t] += red[t+st]; __syncthreads(); }
  float L = red[0];
  float* po = part + ((size_t)((b*NHEAD+h)*32 + cx))*66;
  if (t==0){ po[0]=M; po[1]=L; }
  if (t < 64){
    float o = 0.f;
    #pragma unroll 4
    for (int i=0;i<128;i++)
      o += ps[i] * bf2f(VG[((size_t)(b*NS + cx*128 + i))*HIDN + h*DHEAD + t]);
    po[2+t] = o;
  }
}

__global__ __launch_bounds__(64) void gattn_reduce(const float* __restrict__ part,
    unsigned short* __restrict__ Out){
  int bh = blockIdx.x;
  int b = bh / NHEAD, h = bh % NHEAD;
  int d = threadIdx.x;
  const float* pp = part + (size_t)bh*32*66;
  float M = -1e30f;
  for (int c2=0;c2<32;c2++) M = fmaxf(M, pp[c2*66]);
  float L = 0.f, o = 0.f;
  for (int c2=0;c2<32;c2++){
    float w = __expf(pp[c2*66] - M);
    L += pp[c2*66+1]*w;
    o += pp[c2*66+2+d]*w;
  }
  Out[((size_t)b*NS)*HIDN + h*DHEAD + d] = f2bf(o / L);
}

// ---------------- classification head on CLS token (all fp32) ----------------
__global__ __launch_bounds__(256) void head_k(const float* __restrict__ X,
    const float* __restrict__ HW, const float* __restrict__ HB,
    float* __restrict__ Outp){
  int n = blockIdx.x*256 + threadIdx.x;
  int b = blockIdx.y;
  if (n >= NLABEL) return;
  const float* x0 = X + (size_t)b*NS*HIDN;
  float a = HB[n];
  #pragma unroll 8
  for (int d=0; d<HIDN; d++) a += x0[d] * HW[(size_t)d*NLABEL + n];
  Outp[(size_t)b*NLABEL + n] = a;
}

extern "C" void kernel_launch(void* const* d_in, const int* in_sizes, int n_in,
                              void* d_out, int out_size, void* d_ws, size_t ws_size,
                              hipStream_t stream){
  (void)in_sizes; (void)n_in; (void)out_size; (void)ws_size;
  const int* ids = (const int*)d_in[0];
  const int* am  = (const int*)d_in[1];
  const float* we  = (const float*)d_in[2];
  const float* pe  = (const float*)d_in[3];
  const float* elns= (const float*)d_in[4];
  const float* elnb= (const float*)d_in[5];
  const float* Wq  = (const float*)d_in[6];
  const float* bq  = (const float*)d_in[7];
  const float* Wk  = (const float*)d_in[8];
  const float* bk  = (const float*)d_in[9];
  const float* Wv  = (const float*)d_in[10];
  const float* bv  = (const float*)d_in[11];
  const float* Wqg = (const float*)d_in[12];
  const float* bqg = (const float*)d_in[13];
  const float* Wkg = (const float*)d_in[14];
  const float* bkg = (const float*)d_in[15];
  const float* Wvg = (const float*)d_in[16];
  const float* bvg = (const float*)d_in[17];
  const float* Wo  = (const float*)d_in[18];
  const float* bo  = (const float*)d_in[19];
  const float* l1s = (const float*)d_in[20];
  const float* l1b = (const float*)d_in[21];
  const float* W1  = (const float*)d_in[22];
  const float* b1  = (const float*)d_in[23];
  const float* W2  = (const float*)d_in[24];
  const float* b2  = (const float*)d_in[25];
  const float* l2s = (const float*)d_in[26];
  const float* l2b = (const float*)d_in[27];
  const float* hW  = (const float*)d_in[28];
  const float* hB  = (const float*)d_in[29];

  char* ws = (char*)d_ws;
  float* x = (float*)ws;                                    // 25,165,824 B
  float* y = (float*)(ws + 25165824);                       // 25,165,824 B
  unsigned short* xb = (unsigned short*)(ws + 50331648);    // 12,582,912 B
  unsigned short* qb = (unsigned short*)(ws + 62914560);
  unsigned short* kbuf = (unsigned short*)(ws + 75497472);
  unsigned short* vbuf = (unsigned short*)(ws + 88080384);
  unsigned short* qg0b = (unsigned short*)(ws + 100663296); // 2*128*768*2 = 393,216 B
  float* part = (float*)(ws + 101056512);                   // 2*12*32*66*4 = 202,752 B
  unsigned short* kgb = (unsigned short*)(ws + 113246208);
  unsigned short* vgb = (unsigned short*)(ws + 125829120);
  unsigned short* ao = (unsigned short*)(ws + 138412032);   // 12,582,912 B
  unsigned short* hbuf = (unsigned short*)(ws + 150994944); // 50,331,648 B
  unsigned short* wt = (unsigned short*)(ws + 201326592);   // 35,389,440 B

  const size_t SQ = 589824;        // 768*768
  const size_t SW = 2359296;       // 768*3072
  const size_t PERL = 7*SQ + 2*SW;

  auto tr = [&](const float* src, unsigned short* dst, int R, int C){
    dim3 g(C/32, R/32), blk(32, 8);
    transpose_k<<<g, blk, 0, stream>>>(src, dst, R, C);
  };
  for (int l=0; l<NLAYER; l++){
    unsigned short* base = wt + (size_t)l*PERL;
    tr(Wq  + (size_t)l*SQ, base + 0*SQ, 768, 768);
    tr(Wk  + (size_t)l*SQ, base + 1*SQ, 768, 768);
    tr(Wv  + (size_t)l*SQ, base + 2*SQ, 768, 768);
    tr(Wqg + (size_t)l*SQ, base + 3*SQ, 768, 768);
    tr(Wkg + (size_t)l*SQ, base + 4*SQ, 768, 768);
    tr(Wvg + (size_t)l*SQ, base + 5*SQ, 768, 768);
    tr(Wo  + (size_t)l*SQ, base + 6*SQ, 768, 768);
    tr(W1  + (size_t)l*SW, base + 7*SQ, 768, 3072);
    tr(W2  + (size_t)l*SW, base + 7*SQ + SW, 3072, 768);
  }

  embed_k<<<(NBS*HIDN)/256, 256, 0, stream>>>(ids, we, pe, y);
  ln_k<<<NBS, 256, 0, stream>>>(y, nullptr, elns, elnb, x, xb);

  for (int l=0; l<NLAYER; l++){
    unsigned short* base = wt + (size_t)l*PERL;
    dim3 gp(6, 64);   // N=768, M=8192
    gemm128<0,0><<<gp, 256, 0, stream>>>(xb, base + 0*SQ, bq  + l*768, qb,   NBS, 768, 768);
    gemm128<0,0><<<gp, 256, 0, stream>>>(xb, base + 1*SQ, bk  + l*768, kbuf, NBS, 768, 768);
    gemm128<0,0><<<gp, 256, 0, stream>>>(xb, base + 2*SQ, bv  + l*768, vbuf, NBS, 768, 768);
    gemm128<0,0><<<gp, 256, 0, stream>>>(xb, base + 4*SQ, bkg + l*768, kgb,  NBS, 768, 768);
    gemm128<0,0><<<gp, 256, 0, stream>>>(xb, base + 5*SQ, bvg + l*768, vgb,  NBS, 768, 768);
    // qg needed only for CLS row: project first 128 rows of each batch
    for (int b=0; b<NB; b++)
      gemm128<0,0><<<dim3(6,1), 256, 0, stream>>>(xb + (size_t)b*NS*HIDN, base + 3*SQ,
                                                  bqg + l*768, qg0b + (size_t)b*128*HIDN,
                                                  128, 768, 768);
    band_attn_mfma<<<NB*NHEAD*NCHUNK, 256, 0, stream>>>(qb, kbuf, vbuf, kgb, vgb, am, ao);
    gattn_part<<<dim3(32, NHEAD, NB), 128, 0, stream>>>(qg0b, kgb, vgb, am, part);
    gattn_reduce<<<NB*NHEAD, 64, 0, stream>>>(part, ao);
    gemm128<1,0><<<gp, 256, 0, stream>>>(ao, base + 6*SQ, bo + l*768, y, NBS, 768, 768);
    ln_k<<<NBS, 256, 0, stream>>>(y, x, l1s + l*768, l1b + l*768, x, xb);
    gemm128<0,1><<<dim3(24,64), 256, 0, stream>>>(xb, base + 7*SQ, b1 + l*3072, hbuf, NBS, 3072, 768);
    gemm128<1,0><<<dim3(6,64), 256, 0, stream>>>(hbuf, base + 7*SQ + SW, b2 + l*768, y, NBS, 768, 3072);
    ln_k<<<NBS, 256, 0, stream>>>(y, x, l2s + l*768, l2b + l*768, x, xb);
  }

  head_k<<<dim3((NLABEL+255)/256, NB), 256, 0, stream>>>(x, hW, hB, (float*)d_out);
}